// Round 14
// baseline (86.122 us; speedup 1.0000x reference)
//
#include <hip/hip_runtime.h>

#define Bn 128
#define Qn 32
#define Dn 512
#define En 300
#define Kn 21
#define NC 16                  // 32-doc chunks per batch
#define CH 32
#define NKT 10                 // k-tiles of 32 floats (320 >= 300, zero-padded)
#define SIMLD 36               // sim row stride (floats)
#define NTHR 256
#define QK (Qn * Kn)

typedef __attribute__((ext_vector_type(8))) short bf16x8;
typedef __attribute__((ext_vector_type(4))) float f32x4;

// LDS (bytes): sim float[32][SIMLD] @0 (4608); invq[32] @4608; invd[32] @4736
#define INVQ_OFF 4608
#define INVD_OFF 4736
#define SMEM_BYTES 4864

__device__ __forceinline__ float dot4(float4 a, float4 b) {
    return a.x * b.x + a.y * b.y + a.z * b.z + a.w * b.w;
}

// 8 raw CONTIGUOUS floats -> bf16x8, round-half-up (validated R4-R13)
__device__ __forceinline__ bf16x8 pack8r(float4 lo, float4 hi) {
    uint4 u;
    u.x = __builtin_amdgcn_perm(__float_as_uint(lo.y) + 0x8000u,
                                __float_as_uint(lo.x) + 0x8000u, 0x07060302u);
    u.y = __builtin_amdgcn_perm(__float_as_uint(lo.w) + 0x8000u,
                                __float_as_uint(lo.z) + 0x8000u, 0x07060302u);
    u.z = __builtin_amdgcn_perm(__float_as_uint(hi.y) + 0x8000u,
                                __float_as_uint(hi.x) + 0x8000u, 0x07060302u);
    u.w = __builtin_amdgcn_perm(__float_as_uint(hi.w) + 0x8000u,
                                __float_as_uint(hi.z) + 0x8000u, 0x07060302u);
    union { uint4 u4; bf16x8 v; } cv; cv.u4 = u;
    return cv.v;
}

__global__ __launch_bounds__(NTHR, 4)
void knrm_main(const int* __restrict__ qidx, const int* __restrict__ didx,
               const int* __restrict__ dlen_arr, const float* __restrict__ table,
               float* __restrict__ partial)
{
    // XCD-contiguous remap (2048 % 8 == 0, bijective): a batch's 16 blocks share an XCD
    const int g = blockIdx.x;
    const int idx2 = (g & 7) * 256 + (g >> 3);
    const int b = idx2 >> 4;
    const int c = idx2 & 15;
    const int dlen = dlen_arr[b];
    if (c * CH >= dlen) return;      // inactive: reduce kernel never reads this slice

    const int t = threadIdx.x;
    const int lane = t & 63;
    const int w = t >> 6;            // wave -> (qt, dt) quadrant of the 32x32 sim tile
    const int qt = w >> 1;
    const int dt = w & 1;
    const int frow = lane & 15;
    const int koct = lane >> 4;

    __shared__ __align__(16) char smem[SMEM_BYTES];
    float* sim    = (float*)smem;
    float* invq_s = (float*)(smem + INVQ_OFF);
    float* invd_s = (float*)(smem + INVD_OFF);

    // ---- tokens: direct per-lane loads (L1 dedups the 4x duplication)
    const int qtok = qidx[b * Qn + qt * 16 + frow];
    const int doc = c * CH + dt * 16 + frow;
    const bool dvalid = (doc < dlen);
    const int dtok = dvalid ? didx[b * Dn + doc] : -1;
    const float* qrow = table + (size_t)qtok * En;
    const float* drow = table + (size_t)dtok * En;
    const float4 z4 = make_float4(0.f, 0.f, 0.f, 0.f);

    // ---- register pipeline: 2-stage dbuf, static kt&1 indexing (rule #20 safe)
    float4 qa[2], qb[2], da[2], db[2];
    #define LOADQD(s, KT)                                                          \
        {                                                                          \
            const int f0 = (KT) * 32 + koct * 8;                                   \
            qa[s] = (f0 <= 296) ? *(const float4*)(qrow + f0) : z4;                \
            qb[s] = (f0 <= 292) ? *(const float4*)(qrow + f0 + 4) : z4;            \
            da[s] = (f0 <= 296 && dtok >= 0) ? *(const float4*)(drow + f0) : z4;   \
            db[s] = (f0 <= 292 && dtok >= 0) ? *(const float4*)(drow + f0 + 4) : z4; \
        }

    LOADQD(0, 0)
    f32x4 accS = {0.f, 0.f, 0.f, 0.f};
    float ssq = 0.f, ssd = 0.f;
    #pragma unroll
    for (int kt = 0; kt < NKT; ++kt) {
        const int cur = kt & 1;
        const int nxt = cur ^ 1;
        if (kt + 1 < NKT) LOADQD(nxt, kt + 1)        // prefetch next k-tile
        ssq += dot4(qa[cur], qa[cur]) + dot4(qb[cur], qb[cur]);
        ssd += dot4(da[cur], da[cur]) + dot4(db[cur], db[cur]);
        const bf16x8 af = pack8r(qa[cur], qb[cur]);  // raw bf16; scale applied post-MFMA
        const bf16x8 bf = pack8r(da[cur], db[cur]);
        accS = __builtin_amdgcn_mfma_f32_16x16x32_bf16(af, bf, accS, 0, 0, 0);
    }

    // ---- row norms: lane holds koct-slice sums of row frow; reduce across koct
    ssq += __shfl_xor(ssq, 16); ssq += __shfl_xor(ssq, 32);
    ssd += __shfl_xor(ssd, 16); ssd += __shfl_xor(ssd, 32);
    if (koct == 0 && dt == 0) invq_s[qt * 16 + frow] = 1.0f / fmaxf(sqrtf(ssq), 1e-12f);
    if (koct == 0 && qt == 0) invd_s[dt * 16 + frow] = 1.0f / fmaxf(sqrtf(ssd), 1e-12f);

    // ---- raw sim write (C layout: col=frow -> doc, row=koct*4+r -> q)
    #pragma unroll
    for (int r = 0; r < 4; ++r)
        sim[(qt * 16 + koct * 4 + r) * SIMLD + dt * 16 + frow] = accS[r];
    __syncthreads();                 // the ONLY block barrier

    // ---- pooling: thread = (q row, k-triple); normalize while streaming
    const int pq = t >> 3;
    const int kg = t & 7;
    if (kg < 7) {
        float mu[3], cf[3];
        #pragma unroll
        for (int kk = 0; kk < 3; ++kk) {
            const int k = kg * 3 + kk;
            mu[kk] = (k == 0) ? 1.0f : 1.05f - 0.1f * (float)k;
            cf[kk] = (k == 0) ? -500000.0f : -50.0f;   // -1/(2*sigma^2)
        }
        float acc[3] = {0.f, 0.f, 0.f};
        const float iq = invq_s[pq];
        const int cbase = c * CH;
        #pragma unroll
        for (int f4 = 0; f4 < 8; ++f4) {
            const float4 sv  = *(const float4*)&sim[pq * SIMLD + f4 * 4];
            const float4 id4 = *(const float4*)&invd_s[f4 * 4];
            #pragma unroll
            for (int e = 0; e < 4; ++e) {
                const float se = (e == 0) ? sv.x * id4.x : (e == 1) ? sv.y * id4.y
                               : (e == 2) ? sv.z * id4.z : sv.w * id4.w;
                const float s = (cbase + f4 * 4 + e < dlen) ? se * iq : 1.0e3f;  // masked -> 0
                #pragma unroll
                for (int kk = 0; kk < 3; ++kk) {
                    const float d = s - mu[kk];
                    acc[kk] += __expf(cf[kk] * d * d);
                }
            }
        }
        float* pb = partial + (size_t)(b * NC + c) * QK + pq * Kn + kg * 3;
        pb[0] = acc[0]; pb[1] = acc[1]; pb[2] = acc[2];
    }
}

__global__ __launch_bounds__(704)
void knrm_reduce(const int* __restrict__ qlen_arr, const int* __restrict__ dlen_arr,
                 const float* __restrict__ partial, const float* __restrict__ dense_w,
                 const float* __restrict__ dense_b, float* __restrict__ out)
{
    __shared__ float sq[QK];
    __shared__ float lk[Kn];
    const int b = blockIdx.x;
    const int t = threadIdx.x;
    const int qlen = qlen_arr[b];
    const int ncu = min((dlen_arr[b] + CH - 1) >> 5, NC);   // only written slices
    if (t < QK) {
        const int q = t / Kn;
        float s = 0.f;
        for (int c = 0; c < ncu; ++c)
            s += partial[(size_t)(b * NC + c) * QK + t];
        sq[t] = (q < qlen) ? 0.01f * logf(fmaxf(s, 1e-10f)) : 0.f;
    }
    __syncthreads();
    if (t < Kn) {
        float l = 0.f;
        #pragma unroll
        for (int q = 0; q < Qn; ++q) l += sq[q * Kn + t];
        out[Bn + (size_t)b * Kn + t] = l;   // log_pooling_sum (B,K)
        lk[t] = l;
    }
    __syncthreads();
    if (t == 0) {
        float sc = dense_b[0];
        #pragma unroll
        for (int k = 0; k < Kn; ++k) sc += lk[k] * dense_w[k];
        out[b] = sc;                        // score (B,)
    }
}

extern "C" void kernel_launch(void* const* d_in, const int* in_sizes, int n_in,
                              void* d_out, int out_size, void* d_ws, size_t ws_size,
                              hipStream_t stream)
{
    const int*   qidx  = (const int*)d_in[0];
    const int*   didx  = (const int*)d_in[1];
    const int*   qlen  = (const int*)d_in[2];
    const int*   dlen  = (const int*)d_in[3];
    const float* table = (const float*)d_in[4];
    const float* dw    = (const float*)d_in[5];
    const float* db    = (const float*)d_in[6];
    float* out     = (float*)d_out;
    float* partial = (float*)d_ws;   // 5.5 MB; only slices with c < ceil(dlen/32) are read

    knrm_main<<<dim3(Bn * NC), dim3(NTHR), 0, stream>>>(qidx, didx, dlen, table, partial);
    knrm_reduce<<<dim3(Bn), dim3(704), 0, stream>>>(qlen, dlen, partial, dw, db, out);
}

// Round 15
// 41.879 us; speedup vs baseline: 2.0564x; 2.0564x over previous
//
#include <hip/hip_runtime.h>

#define Bn 128
#define Qn 32
#define Dn 512
#define En 300
#define Kn 21
#define DR 128                 // docs per round
#define NRMAX 4                // max rounds (512/128)
#define NKT 10                 // k-tiles of 32 floats (320 >= 300, zero-padded)
#define LDE 40                 // shorts per row within one k-tile (80 B)
#define QTILE (Qn * LDE)       // 1280 shorts
#define DTILE (DR * LDE)       // 5120 shorts
#define SIMLD 36
#define NTHR 1024

typedef __attribute__((ext_vector_type(8))) short bf16x8;
typedef __attribute__((ext_vector_type(4))) float f32x4;

// LDS map (bytes):
//   dbuf [0, 102400)        short[10][128][40]
//   qbuf [102400, 128000)   short[10][32][40]
//   simb [128000, 146432)   float[4][32][36]  (per wave-group)
//   pool/sq/lk alias dbuf (dead after last MFMA)
#define QBUF_OFF 102400
#define SIM_OFF  128000
#define SMEM_BYTES 146432      // 143 KB static (<160 KB; R1 validated >64 KB)

__device__ __forceinline__ float dot4(float4 a, float4 b) {
    return a.x * b.x + a.y * b.y + a.z * b.z + a.w * b.w;
}

#define ISSUE(arr, tok)                                                        \
    _Pragma("unroll")                                                          \
    for (int j2 = 0; j2 < NKT; ++j2) {                                         \
        const int k = j2 * 32 + il * 4;                                        \
        float4 v = {0.f, 0.f, 0.f, 0.f};                                       \
        if (k <= 296 && (tok) >= 0)                                            \
            v = *(const float4*)(table + (size_t)(tok) * En + k);              \
        arr[j2] = v;                                                           \
    }

// octet (8 threads) row-norm + bf16 pack + 8B LDS writes (R7/R9-proven)
#define COMMIT(arr, dst, TS)                                                   \
    {                                                                          \
        float ss = 0.f;                                                        \
        _Pragma("unroll")                                                      \
        for (int j2 = 0; j2 < NKT; ++j2) ss += dot4(arr[j2], arr[j2]);         \
        ss += __shfl_xor(ss, 1);                                               \
        ss += __shfl_xor(ss, 2);                                               \
        ss += __shfl_xor(ss, 4);                                               \
        const float inv = 1.0f / fmaxf(sqrtf(ss), 1e-12f);                     \
        _Pragma("unroll")                                                      \
        for (int j2 = 0; j2 < NKT; ++j2) {                                     \
            const unsigned ax = __float_as_uint(arr[j2].x * inv) + 0x8000u;    \
            const unsigned ay = __float_as_uint(arr[j2].y * inv) + 0x8000u;    \
            const unsigned az = __float_as_uint(arr[j2].z * inv) + 0x8000u;    \
            const unsigned aw = __float_as_uint(arr[j2].w * inv) + 0x8000u;    \
            uint2 p;                                                           \
            p.x = __builtin_amdgcn_perm(ay, ax, 0x07060302u);                  \
            p.y = __builtin_amdgcn_perm(aw, az, 0x07060302u);                  \
            *(uint2*)&(dst)[j2 * (TS) + row * LDE + il * 4] = p;               \
        }                                                                      \
    }

__global__ __launch_bounds__(NTHR, 1)
void knrm_fused(const int* __restrict__ qidx, const int* __restrict__ didx,
                const int* __restrict__ qlen_arr, const int* __restrict__ dlen_arr,
                const float* __restrict__ table, const float* __restrict__ dense_w,
                const float* __restrict__ dense_b, float* __restrict__ out)
{
    const int b = blockIdx.x;
    const int dlen = dlen_arr[b];
    const int qlen = qlen_arr[b];
    const int t = threadIdx.x;

    __shared__ __align__(16) char smem[SMEM_BYTES];
    short* dbuf = (short*)smem;
    short* qbuf = (short*)(smem + QBUF_OFF);
    float* simb = (float*)(smem + SIM_OFF);
    float* pool = (float*)smem;                 // aliases (live after last MFMA)
    float* sq   = (float*)(smem + 10752);
    float* lk   = (float*)(smem + 13440);

    const int lane = t & 63;
    const int w  = t >> 6;       // wave 0..15
    const int gg = w >> 2;       // wave-group 0..3 (owns a 32-doc chunk per round)
    const int wq = w & 3;        // quadrant within group
    const int qt = wq >> 1;
    const int dt = wq & 1;
    const int frow = lane & 15;
    const int koct = lane >> 4;
    const int row = t >> 3;      // staging row (q: 0..31 for t<256; d: 0..127)
    const int il  = t & 7;

    // ---- prologue: issue round-0 doc loads + q loads, commit both, one barrier
    float4 ld[NKT];
    int dtok = (row < dlen) ? didx[b * Dn + row] : -1;
    ISSUE(ld, dtok)
    if (t < 256) {
        float4 lq[NKT];
        const int qtok = qidx[b * Qn + row];
        ISSUE(lq, qtok)
        COMMIT(lq, qbuf, QTILE)
    }
    COMMIT(ld, dbuf, DTILE)
    __syncthreads();             // qbuf + dbuf(round 0) ready

    // ---- hoist loop-invariant q fragments
    bf16x8 af[NKT];
    #pragma unroll
    for (int kt = 0; kt < NKT; ++kt)
        af[kt] = *(const bf16x8*)&qbuf[kt * QTILE + (qt * 16 + frow) * LDE + koct * 8];

    // ---- pooling constants (thread = (q row, k-triple) within its group)
    const int u  = t & 255;
    const int pq = u >> 3;
    const int kg = u & 7;
    float mu[3], cf[3];
    #pragma unroll
    for (int kk = 0; kk < 3; ++kk) {
        const int k = kg * 3 + kk;
        mu[kk] = (k == 0) ? 1.0f : 1.05f - 0.1f * (float)k;
        cf[kk] = (k == 0) ? -500000.0f : -50.0f;   // -1/(2*sigma^2)
    }
    float acc[3] = {0.f, 0.f, 0.f};

    const int nr = min((dlen + DR - 1) >> 7, NRMAX);
    for (int it = 0; it < nr; ++it) {
        const bool more = (it + 1 < nr);
        if (more) {                                  // issue next round early
            const int d1 = (it + 1) * DR + row;
            dtok = (d1 < dlen) ? didx[b * Dn + d1] : -1;
            ISSUE(ld, dtok)
        }

        // ---- 10 MFMAs: group gg reads its 32-row slice of dbuf
        f32x4 accS = {0.f, 0.f, 0.f, 0.f};
        #pragma unroll
        for (int kt = 0; kt < NKT; ++kt) {
            const bf16x8 bf = *(const bf16x8*)
                &dbuf[kt * DTILE + (gg * 32 + dt * 16 + frow) * LDE + koct * 8];
            accS = __builtin_amdgcn_mfma_f32_16x16x32_bf16(af[kt], bf, accS, 0, 0, 0);
        }
        // C layout: col=frow (doc), row=koct*4+r (q)
        #pragma unroll
        for (int r = 0; r < 4; ++r)
            simb[gg * (Qn * SIMLD) + (qt * 16 + koct * 4 + r) * SIMLD + dt * 16 + frow] = accS[r];
        __syncthreads();         // sim ready; dbuf reads done

        if (more) COMMIT(ld, dbuf, DTILE)            // overwrite dbuf for next round

        // ---- pool this round's 32 docs of group gg
        if (kg < 7) {
            const int docg = it * DR + gg * 32;
            #pragma unroll
            for (int f4 = 0; f4 < 8; ++f4) {
                const float4 sv = *(const float4*)&simb[gg * (Qn * SIMLD) + pq * SIMLD + f4 * 4];
                #pragma unroll
                for (int e = 0; e < 4; ++e) {
                    const float se = (e == 0) ? sv.x : (e == 1) ? sv.y : (e == 2) ? sv.z : sv.w;
                    const float s = (docg + f4 * 4 + e < dlen) ? se : 1.0e3f;  // masked -> 0
                    #pragma unroll
                    for (int kk = 0; kk < 3; ++kk) {
                        const float d = s - mu[kk];
                        acc[kk] += __expf(cf[kk] * d * d);
                    }
                }
            }
        }
        __syncthreads();         // pool reads done; dbuf safe for next MFMA
    }

    // ---- finalize in-block (dbuf dead -> pool/sq/lk aliases live)
    if (kg < 7) {
        float* pb = pool + gg * 672 + pq * Kn + kg * 3;
        pb[0] = acc[0]; pb[1] = acc[1]; pb[2] = acc[2];
    }
    __syncthreads();
    if (t < Qn * Kn) {
        const int q = t / Kn;
        const float s = pool[t] + pool[672 + t] + pool[1344 + t] + pool[2016 + t];
        sq[t] = (q < qlen) ? 0.01f * logf(fmaxf(s, 1e-10f)) : 0.f;
    }
    __syncthreads();
    if (t < Kn) {
        float l = 0.f;
        #pragma unroll
        for (int q = 0; q < Qn; ++q) l += sq[q * Kn + t];
        out[Bn + (size_t)b * Kn + t] = l;   // log_pooling_sum (B,K)
        lk[t] = l;
    }
    __syncthreads();
    if (t == 0) {
        float sc = dense_b[0];
        #pragma unroll
        for (int k = 0; k < Kn; ++k) sc += lk[k] * dense_w[k];
        out[b] = sc;                        // score (B,)
    }
}

extern "C" void kernel_launch(void* const* d_in, const int* in_sizes, int n_in,
                              void* d_out, int out_size, void* d_ws, size_t ws_size,
                              hipStream_t stream)
{
    const int*   qidx  = (const int*)d_in[0];
    const int*   didx  = (const int*)d_in[1];
    const int*   qlen  = (const int*)d_in[2];
    const int*   dlen  = (const int*)d_in[3];
    const float* table = (const float*)d_in[4];
    const float* dw    = (const float*)d_in[5];
    const float* db    = (const float*)d_in[6];
    float* out = (float*)d_out;

    knrm_fused<<<dim3(Bn), dim3(NTHR), 0, stream>>>(qidx, didx, qlen, dlen, table, dw, db, out);
}